// Round 2
// baseline (129.641 us; speedup 1.0000x reference)
//
#include <hip/hip_runtime.h>
#include <cstddef>

// B=256, N=256, F=128 everywhere.

typedef __attribute__((ext_vector_type(8))) short short8;
typedef __attribute__((ext_vector_type(4))) float f32x4;

static __device__ __forceinline__ unsigned short f2bf(float f) {
  unsigned int u = __float_as_uint(f);
  u += 0x7FFFu + ((u >> 16) & 1u);   // round-nearest-even to bf16
  return (unsigned short)(u >> 16);
}

static __device__ __forceinline__ f32x4 mfma16(short8 a, short8 b, f32x4 c) {
  return __builtin_amdgcn_mfma_f32_16x16x32_bf16(a, b, c, 0, 0, 0);
}

// ---------------- kernel 1: degree + bf16 convert (diag := 1) ----------------
// Looping form: 2048 blocks x 4 waves; each wave owns 8 consecutive rows.
// All 8 float4 loads issued up front (ILP), 8 independent shuffle chains.
__global__ __launch_bounds__(256) void k_deg_conv(
    const float* __restrict__ adj, unsigned short* __restrict__ Abf,
    float* __restrict__ dinv) {
  const int wid = (blockIdx.x << 2) + (threadIdx.x >> 6);  // wave id 0..8191
  const int t = threadIdx.x & 63;
  const int row0 = wid << 3;                               // 8 rows per wave
  const size_t base0 = (size_t)row0 * 256;
  const int c0 = 4 * t;

  float4 v[8];
  #pragma unroll
  for (int r = 0; r < 8; ++r)
    v[r] = *reinterpret_cast<const float4*>(adj + base0 + (size_t)r * 256 + c0);

  float s[8];
  #pragma unroll
  for (int r = 0; r < 8; ++r) {
    const int n = (row0 + r) & 255;
    if (n >= c0 && n < c0 + 4) reinterpret_cast<float*>(&v[r])[n - c0] = 1.0f;
    s[r] = v[r].x + v[r].y + v[r].z + v[r].w;
  }
  #pragma unroll
  for (int off = 32; off >= 1; off >>= 1) {
    #pragma unroll
    for (int r = 0; r < 8; ++r) s[r] += __shfl_xor(s[r], off);
  }

  // lane r stores dinv for row r (select chain keeps indices compile-time)
  float sel = s[0];
  #pragma unroll
  for (int r = 1; r < 8; ++r) sel = (t == r) ? s[r] : sel;
  if (t < 8) dinv[row0 + t] = rsqrtf(fmaxf(sel, 1.0f));

  #pragma unroll
  for (int r = 0; r < 8; ++r) {
    ushort4 o;
    o.x = f2bf(v[r].x); o.y = f2bf(v[r].y);
    o.z = f2bf(v[r].z); o.w = f2bf(v[r].w);
    *reinterpret_cast<ushort4*>(Abf + base0 + (size_t)r * 256 + c0) = o;
  }
}

// ---------------- kernel 2: pack W (128x128 f32) into A-fragment order -------
// A operand is W^T: frag elem j = W[ks*32+(l>>4)*8+j][r*16+(l&15)]
// stored contiguously at P[((ks*8+r)*64+l)*8 + j]. Grid 32 blocks x 64 thr.
__global__ __launch_bounds__(64) void k_packW(
    const float* __restrict__ W, unsigned short* __restrict__ P) {
  const int ks = blockIdx.x >> 3;
  const int r = blockIdx.x & 7;
  const int l = threadIdx.x;
  const int col = r * 16 + (l & 15);
  const int k0 = ks * 32 + ((l >> 4) << 3);
  short8 frag;
  #pragma unroll
  for (int j = 0; j < 8; ++j)
    frag[j] = (short)f2bf(W[(size_t)(k0 + j) * 128 + col]);
  *reinterpret_cast<short8*>(P + ((size_t)((ks * 8 + r) * 64 + l)) * 8) = frag;
}

// ---------------- kernel 3/5: feature GEMM, transposed output ----------------
// Computes Tt[b][f][m] = dinv[m] * sum_k In[m][k] * W[k][f]  (bf16 out).
// MFMA: M=f (8 row-tiles), N=m (wave owns 16 cols), K=128 (4 ksteps).
static __device__ __forceinline__ short8 load_bfrag(const float* p) {
  float4 u = *reinterpret_cast<const float4*>(p);
  float4 v = *reinterpret_cast<const float4*>(p + 4);
  short8 f;
  f[0] = (short)f2bf(u.x); f[1] = (short)f2bf(u.y);
  f[2] = (short)f2bf(u.z); f[3] = (short)f2bf(u.w);
  f[4] = (short)f2bf(v.x); f[5] = (short)f2bf(v.y);
  f[6] = (short)f2bf(v.z); f[7] = (short)f2bf(v.w);
  return f;
}
static __device__ __forceinline__ short8 load_bfrag(const unsigned short* p) {
  return *reinterpret_cast<const short8*>(p);
}

template <typename TIn>
__global__ __launch_bounds__(256) void k_feat(
    const TIn* __restrict__ In,            // [B*256, 128]
    const unsigned short* __restrict__ Wp, // packed fragments
    const float* __restrict__ dinv,        // [B*256]
    unsigned short* __restrict__ Tt) {     // [B,128,256] bf16
  const int tid = threadIdx.x;
  const int w = tid >> 6;
  const int l = tid & 63;
  const int l15 = l & 15;
  const int m_lane = blockIdx.x * 64 + w * 16 + l15;  // global row index
  const int khalf = (l >> 4) << 3;
  const short8* WpF = reinterpret_cast<const short8*>(Wp);

  f32x4 acc[8];
  #pragma unroll
  for (int r = 0; r < 8; ++r) acc[r] = (f32x4)(0.0f);

  #pragma unroll
  for (int ks = 0; ks < 4; ++ks) {
    const int k0 = ks * 32 + khalf;
    short8 bfrag = load_bfrag(In + (size_t)m_lane * 128 + k0);
    #pragma unroll
    for (int r = 0; r < 8; ++r) {
      short8 afr = WpF[(ks * 8 + r) * 64 + l];
      acc[r] = mfma16(afr, bfrag, acc[r]);
    }
  }

  const float scale = dinv[m_lane];
  const int b = m_lane >> 8;
  const int m_in_b = m_lane & 255;
  const int qbase = (l >> 4) << 2;
  #pragma unroll
  for (int r = 0; r < 8; ++r) {
    #pragma unroll
    for (int q = 0; q < 4; ++q) {
      const int f = r * 16 + qbase + q;
      Tt[((size_t)(b * 128 + f) << 8) + m_in_b] = f2bf(acc[r][q] * scale);
    }
  }
}

// ---------------- kernel 4/6: aggregation (+ fused pool + readout) -----------
// Per batch: H[n][f] = dinv[n] * sum_m Abf[n][m] * Tt[f][m] + bias[f]
// 512 threads = 8 waves; wave owns 32 n-rows x 128 f. K=256 in 8 ksteps.
template <bool POOL>
__global__ __launch_bounds__(512) void k_agg(
    const unsigned short* __restrict__ Abf,  // [B,256,256]
    const unsigned short* __restrict__ Tt,   // [B,128,256]
    const float* __restrict__ dinv,          // [B*256]
    const float* __restrict__ bias,          // [128]
    unsigned short* __restrict__ Hout,       // [B*256,128] bf16 (!POOL)
    const float* __restrict__ Wr,            // [256,128] (POOL)
    const float* __restrict__ br,            // [128]     (POOL)
    float* __restrict__ Out) {               // [B,128]   (POOL)
  __shared__ float lds_sum[8][128];
  __shared__ float lds_max[8][128];
  __shared__ float pooled_s[256];

  const int b = blockIdx.x;
  const int tid = threadIdx.x;
  const int w = tid >> 6;
  const int l = tid & 63;
  const int l15 = l & 15;
  const int khalf = (l >> 4) << 3;
  const int n0w = w * 32;
  const unsigned short* Ab = Abf + ((size_t)b << 16);
  const unsigned short* Tb = Tt + ((size_t)b << 15);

  f32x4 acc[2][8];
  #pragma unroll
  for (int rt = 0; rt < 2; ++rt)
    #pragma unroll
    for (int c = 0; c < 8; ++c) acc[rt][c] = (f32x4)(0.0f);

  #pragma unroll
  for (int ks = 0; ks < 8; ++ks) {
    const int k0 = ks * 32 + khalf;
    short8 a0 = *reinterpret_cast<const short8*>(Ab + (size_t)(n0w + l15) * 256 + k0);
    short8 a1 = *reinterpret_cast<const short8*>(Ab + (size_t)(n0w + 16 + l15) * 256 + k0);
    #pragma unroll
    for (int c = 0; c < 8; ++c) {
      short8 bf = *reinterpret_cast<const short8*>(Tb + (size_t)(c * 16 + l15) * 256 + k0);
      acc[0][c] = mfma16(a0, bf, acc[0][c]);
      acc[1][c] = mfma16(a1, bf, acc[1][c]);
    }
  }

  const int qbase = (l >> 4) << 2;
  float dv[2][4];
  #pragma unroll
  for (int rt = 0; rt < 2; ++rt)
    #pragma unroll
    for (int q = 0; q < 4; ++q)
      dv[rt][q] = dinv[(b << 8) + n0w + rt * 16 + qbase + q];
  float bs[8];
  #pragma unroll
  for (int c = 0; c < 8; ++c) bs[c] = bias[c * 16 + l15];

  if (!POOL) {
    #pragma unroll
    for (int rt = 0; rt < 2; ++rt) {
      #pragma unroll
      for (int q = 0; q < 4; ++q) {
        const int n = n0w + rt * 16 + qbase + q;
        #pragma unroll
        for (int c = 0; c < 8; ++c) {
          const float v = acc[rt][c][q] * dv[rt][q] + bs[c];
          Hout[((size_t)((b << 8) + n) << 7) + c * 16 + l15] = f2bf(v);
        }
      }
    }
  } else {
    float psum[8], pmax[8];
    #pragma unroll
    for (int c = 0; c < 8; ++c) { psum[c] = 0.0f; pmax[c] = -1e30f; }
    #pragma unroll
    for (int rt = 0; rt < 2; ++rt) {
      #pragma unroll
      for (int q = 0; q < 4; ++q) {
        #pragma unroll
        for (int c = 0; c < 8; ++c) {
          const float v = acc[rt][c][q] * dv[rt][q] + bs[c];
          psum[c] += v;
          pmax[c] = fmaxf(pmax[c], v);
        }
      }
    }
    // reduce across the 4 lane-groups sharing the same f (=c*16+l15)
    #pragma unroll
    for (int c = 0; c < 8; ++c) {
      psum[c] += __shfl_xor(psum[c], 16);
      pmax[c] = fmaxf(pmax[c], __shfl_xor(pmax[c], 16));
      psum[c] += __shfl_xor(psum[c], 32);
      pmax[c] = fmaxf(pmax[c], __shfl_xor(pmax[c], 32));
    }
    if (l < 16) {
      #pragma unroll
      for (int c = 0; c < 8; ++c) {
        lds_sum[w][c * 16 + l] = psum[c];
        lds_max[w][c * 16 + l] = pmax[c];
      }
    }
    __syncthreads();
    if (tid < 128) {
      float s = 0.0f, m = -1e30f;
      #pragma unroll
      for (int ww = 0; ww < 8; ++ww) {
        s += lds_sum[ww][tid];
        m = fmaxf(m, lds_max[ww][tid]);
      }
      pooled_s[tid] = s * (1.0f / 256.0f);
      pooled_s[128 + tid] = m;
    }
    __syncthreads();
    if (tid < 128) {
      float o = br[tid];
      #pragma unroll 8
      for (int i = 0; i < 256; ++i) o = fmaf(pooled_s[i], Wr[(i << 7) + tid], o);
      Out[((size_t)b << 7) + tid] = o;
    }
  }
}

extern "C" void kernel_launch(void* const* d_in, const int* in_sizes, int n_in,
                              void* d_out, int out_size, void* d_ws, size_t ws_size,
                              hipStream_t stream) {
  const float* x   = (const float*)d_in[0];
  const float* adj = (const float*)d_in[1];
  const float* W1  = (const float*)d_in[2];
  const float* b1  = (const float*)d_in[3];
  const float* W2  = (const float*)d_in[4];
  const float* b2  = (const float*)d_in[5];
  const float* Wr  = (const float*)d_in[6];
  const float* br  = (const float*)d_in[7];
  float* out = (float*)d_out;

  char* ws = (char*)d_ws;
  unsigned short* Abf = (unsigned short*)(ws);              // 33,554,432 B
  unsigned short* Tt  = (unsigned short*)(ws + 33554432);   // 16,777,216 B
  unsigned short* H1  = (unsigned short*)(ws + 50331648);   // 16,777,216 B
  float*          dinv = (float*)(ws + 67108864);           //    262,144 B
  unsigned short* W1p = (unsigned short*)(ws + 67371008);   //     32,768 B
  unsigned short* W2p = (unsigned short*)(ws + 67403776);   //     32,768 B

  k_packW<<<32, 64, 0, stream>>>(W1, W1p);
  k_packW<<<32, 64, 0, stream>>>(W2, W2p);
  k_deg_conv<<<2048, 256, 0, stream>>>(adj, Abf, dinv);
  k_feat<float><<<1024, 256, 0, stream>>>(x, W1p, dinv, Tt);
  k_agg<false><<<256, 512, 0, stream>>>(Abf, Tt, dinv, b1, H1, nullptr, nullptr, nullptr);
  k_feat<unsigned short><<<1024, 256, 0, stream>>>(H1, W2p, dinv, Tt);
  k_agg<true><<<256, 512, 0, stream>>>(Abf, Tt, dinv, b2, nullptr, Wr, br, out);
}

// Round 3
// 106.734 us; speedup vs baseline: 1.2146x; 1.2146x over previous
//
#include <hip/hip_runtime.h>
#include <cstddef>

// B=256, N=256, F=128 everywhere.

typedef __attribute__((ext_vector_type(8))) short short8;
typedef __attribute__((ext_vector_type(4))) float f32x4;

static __device__ __forceinline__ unsigned short f2bf(float f) {
  unsigned int u = __float_as_uint(f);
  u += 0x7FFFu + ((u >> 16) & 1u);   // round-nearest-even to bf16
  return (unsigned short)(u >> 16);
}

static __device__ __forceinline__ f32x4 mfma16(short8 a, short8 b, f32x4 c) {
  return __builtin_amdgcn_mfma_f32_16x16x32_bf16(a, b, c, 0, 0, 0);
}

// ---------------- kernel 1: degree + bf16 convert (diag := 1) ----------------
// 2048 blocks x 4 waves; each wave owns 8 consecutive rows (ILP x8).
// Diagonal patch via compile-time component selects — NO runtime vector
// indexing (that forced v[] to scratch last round: +134 MB spill traffic).
__global__ __launch_bounds__(256) void k_deg_conv(
    const float* __restrict__ adj, unsigned short* __restrict__ Abf,
    float* __restrict__ dinv) {
  const int wid = (blockIdx.x << 2) + (threadIdx.x >> 6);  // wave id 0..8191
  const int t = threadIdx.x & 63;
  const int row0 = wid << 3;                               // 8 rows per wave
  const size_t base0 = (size_t)row0 * 256;
  const int c0 = 4 * t;

  float4 v[8];
  #pragma unroll
  for (int r = 0; r < 8; ++r)
    v[r] = *reinterpret_cast<const float4*>(adj + base0 + (size_t)r * 256 + c0);

  float s[8];
  #pragma unroll
  for (int r = 0; r < 8; ++r) {
    const int n = (row0 + r) & 255;
    v[r].x = (n == c0 + 0) ? 1.0f : v[r].x;
    v[r].y = (n == c0 + 1) ? 1.0f : v[r].y;
    v[r].z = (n == c0 + 2) ? 1.0f : v[r].z;
    v[r].w = (n == c0 + 3) ? 1.0f : v[r].w;
    s[r] = (v[r].x + v[r].y) + (v[r].z + v[r].w);
  }
  #pragma unroll
  for (int off = 32; off >= 1; off >>= 1) {
    #pragma unroll
    for (int r = 0; r < 8; ++r) s[r] += __shfl_xor(s[r], off);
  }

  // lane r stores dinv for row r (select chain keeps indices compile-time)
  float sel = s[0];
  #pragma unroll
  for (int r = 1; r < 8; ++r) sel = (t == r) ? s[r] : sel;
  if (t < 8) dinv[row0 + t] = rsqrtf(fmaxf(sel, 1.0f));

  #pragma unroll
  for (int r = 0; r < 8; ++r) {
    ushort4 o;
    o.x = f2bf(v[r].x); o.y = f2bf(v[r].y);
    o.z = f2bf(v[r].z); o.w = f2bf(v[r].w);
    *reinterpret_cast<ushort4*>(Abf + base0 + (size_t)r * 256 + c0) = o;
  }
}

// ---------------- kernel 2: pack W (128x128 f32) into A-fragment order -------
// A operand is W^T: frag elem j = W[ks*32+(l>>4)*8+j][r*16+(l&15)]
// stored contiguously at P[((ks*8+r)*64+l)*8 + j]. Grid 32 blocks x 64 thr.
__global__ __launch_bounds__(64) void k_packW(
    const float* __restrict__ W, unsigned short* __restrict__ P) {
  const int ks = blockIdx.x >> 3;
  const int r = blockIdx.x & 7;
  const int l = threadIdx.x;
  const int col = r * 16 + (l & 15);
  const int k0 = ks * 32 + ((l >> 4) << 3);
  short8 frag;
  #pragma unroll
  for (int j = 0; j < 8; ++j)
    frag[j] = (short)f2bf(W[(size_t)(k0 + j) * 128 + col]);
  *reinterpret_cast<short8*>(P + ((size_t)((ks * 8 + r) * 64 + l)) * 8) = frag;
}

// ---------------- kernel 3/5: feature GEMM, transposed output ----------------
// Computes Tt[b][f][m] = dinv[m] * sum_k In[m][k] * W[k][f]  (bf16 out).
// MFMA: M=f (8 row-tiles), N=m (wave owns 16 cols), K=128 (4 ksteps).
static __device__ __forceinline__ short8 load_bfrag(const float* p) {
  float4 u = *reinterpret_cast<const float4*>(p);
  float4 v = *reinterpret_cast<const float4*>(p + 4);
  short8 f;
  f[0] = (short)f2bf(u.x); f[1] = (short)f2bf(u.y);
  f[2] = (short)f2bf(u.z); f[3] = (short)f2bf(u.w);
  f[4] = (short)f2bf(v.x); f[5] = (short)f2bf(v.y);
  f[6] = (short)f2bf(v.z); f[7] = (short)f2bf(v.w);
  return f;
}
static __device__ __forceinline__ short8 load_bfrag(const unsigned short* p) {
  return *reinterpret_cast<const short8*>(p);
}

template <typename TIn>
__global__ __launch_bounds__(256) void k_feat(
    const TIn* __restrict__ In,            // [B*256, 128]
    const unsigned short* __restrict__ Wp, // packed fragments
    const float* __restrict__ dinv,        // [B*256]
    unsigned short* __restrict__ Tt) {     // [B,128,256] bf16
  const int tid = threadIdx.x;
  const int w = tid >> 6;
  const int l = tid & 63;
  const int l15 = l & 15;
  const int m_lane = blockIdx.x * 64 + w * 16 + l15;  // global row index
  const int khalf = (l >> 4) << 3;
  const short8* WpF = reinterpret_cast<const short8*>(Wp);

  f32x4 acc[8];
  #pragma unroll
  for (int r = 0; r < 8; ++r) acc[r] = (f32x4)(0.0f);

  #pragma unroll
  for (int ks = 0; ks < 4; ++ks) {
    const int k0 = ks * 32 + khalf;
    short8 bfrag = load_bfrag(In + (size_t)m_lane * 128 + k0);
    #pragma unroll
    for (int r = 0; r < 8; ++r) {
      short8 afr = WpF[(ks * 8 + r) * 64 + l];
      acc[r] = mfma16(afr, bfrag, acc[r]);
    }
  }

  const float scale = dinv[m_lane];
  const int b = m_lane >> 8;
  const int m_in_b = m_lane & 255;
  const int qbase = (l >> 4) << 2;
  #pragma unroll
  for (int r = 0; r < 8; ++r) {
    #pragma unroll
    for (int q = 0; q < 4; ++q) {
      const int f = r * 16 + qbase + q;
      Tt[((size_t)(b * 128 + f) << 8) + m_in_b] = f2bf(acc[r][q] * scale);
    }
  }
}

// ---------------- kernel 4/6: aggregation (+ fused pool + readout) -----------
// Per batch: H[n][f] = dinv[n] * sum_m Abf[n][m] * Tt[f][m] + bias[f]
// 512 threads = 8 waves; wave owns 32 n-rows x 128 f. K=256 in 8 ksteps.
template <bool POOL>
__global__ __launch_bounds__(512) void k_agg(
    const unsigned short* __restrict__ Abf,  // [B,256,256]
    const unsigned short* __restrict__ Tt,   // [B,128,256]
    const float* __restrict__ dinv,          // [B*256]
    const float* __restrict__ bias,          // [128]
    unsigned short* __restrict__ Hout,       // [B*256,128] bf16 (!POOL)
    const float* __restrict__ Wr,            // [256,128] (POOL)
    const float* __restrict__ br,            // [128]     (POOL)
    float* __restrict__ Out) {               // [B,128]   (POOL)
  __shared__ float lds_sum[8][128];
  __shared__ float lds_max[8][128];
  __shared__ float pooled_s[256];

  const int b = blockIdx.x;
  const int tid = threadIdx.x;
  const int w = tid >> 6;
  const int l = tid & 63;
  const int l15 = l & 15;
  const int khalf = (l >> 4) << 3;
  const int n0w = w * 32;
  const unsigned short* Ab = Abf + ((size_t)b << 16);
  const unsigned short* Tb = Tt + ((size_t)b << 15);

  f32x4 acc[2][8];
  #pragma unroll
  for (int rt = 0; rt < 2; ++rt)
    #pragma unroll
    for (int c = 0; c < 8; ++c) acc[rt][c] = (f32x4)(0.0f);

  #pragma unroll
  for (int ks = 0; ks < 8; ++ks) {
    const int k0 = ks * 32 + khalf;
    short8 a0 = *reinterpret_cast<const short8*>(Ab + (size_t)(n0w + l15) * 256 + k0);
    short8 a1 = *reinterpret_cast<const short8*>(Ab + (size_t)(n0w + 16 + l15) * 256 + k0);
    #pragma unroll
    for (int c = 0; c < 8; ++c) {
      short8 bf = *reinterpret_cast<const short8*>(Tb + (size_t)(c * 16 + l15) * 256 + k0);
      acc[0][c] = mfma16(a0, bf, acc[0][c]);
      acc[1][c] = mfma16(a1, bf, acc[1][c]);
    }
  }

  const int qbase = (l >> 4) << 2;
  float dv[2][4];
  #pragma unroll
  for (int rt = 0; rt < 2; ++rt)
    #pragma unroll
    for (int q = 0; q < 4; ++q)
      dv[rt][q] = dinv[(b << 8) + n0w + rt * 16 + qbase + q];
  float bs[8];
  #pragma unroll
  for (int c = 0; c < 8; ++c) bs[c] = bias[c * 16 + l15];

  if (!POOL) {
    #pragma unroll
    for (int rt = 0; rt < 2; ++rt) {
      #pragma unroll
      for (int q = 0; q < 4; ++q) {
        const int n = n0w + rt * 16 + qbase + q;
        #pragma unroll
        for (int c = 0; c < 8; ++c) {
          const float v = acc[rt][c][q] * dv[rt][q] + bs[c];
          Hout[((size_t)((b << 8) + n) << 7) + c * 16 + l15] = f2bf(v);
        }
      }
    }
  } else {
    float psum[8], pmax[8];
    #pragma unroll
    for (int c = 0; c < 8; ++c) { psum[c] = 0.0f; pmax[c] = -1e30f; }
    #pragma unroll
    for (int rt = 0; rt < 2; ++rt) {
      #pragma unroll
      for (int q = 0; q < 4; ++q) {
        #pragma unroll
        for (int c = 0; c < 8; ++c) {
          const float v = acc[rt][c][q] * dv[rt][q] + bs[c];
          psum[c] += v;
          pmax[c] = fmaxf(pmax[c], v);
        }
      }
    }
    // reduce across the 4 lane-groups sharing the same f (=c*16+l15)
    #pragma unroll
    for (int c = 0; c < 8; ++c) {
      psum[c] += __shfl_xor(psum[c], 16);
      pmax[c] = fmaxf(pmax[c], __shfl_xor(pmax[c], 16));
      psum[c] += __shfl_xor(psum[c], 32);
      pmax[c] = fmaxf(pmax[c], __shfl_xor(pmax[c], 32));
    }
    if (l < 16) {
      #pragma unroll
      for (int c = 0; c < 8; ++c) {
        lds_sum[w][c * 16 + l] = psum[c];
        lds_max[w][c * 16 + l] = pmax[c];
      }
    }
    __syncthreads();
    if (tid < 128) {
      float s = 0.0f, m = -1e30f;
      #pragma unroll
      for (int ww = 0; ww < 8; ++ww) {
        s += lds_sum[ww][tid];
        m = fmaxf(m, lds_max[ww][tid]);
      }
      pooled_s[tid] = s * (1.0f / 256.0f);
      pooled_s[128 + tid] = m;
    }
    __syncthreads();
    if (tid < 128) {
      float o = br[tid];
      #pragma unroll 8
      for (int i = 0; i < 256; ++i) o = fmaf(pooled_s[i], Wr[(i << 7) + tid], o);
      Out[((size_t)b << 7) + tid] = o;
    }
  }
}

extern "C" void kernel_launch(void* const* d_in, const int* in_sizes, int n_in,
                              void* d_out, int out_size, void* d_ws, size_t ws_size,
                              hipStream_t stream) {
  const float* x   = (const float*)d_in[0];
  const float* adj = (const float*)d_in[1];
  const float* W1  = (const float*)d_in[2];
  const float* b1  = (const float*)d_in[3];
  const float* W2  = (const float*)d_in[4];
  const float* b2  = (const float*)d_in[5];
  const float* Wr  = (const float*)d_in[6];
  const float* br  = (const float*)d_in[7];
  float* out = (float*)d_out;

  char* ws = (char*)d_ws;
  unsigned short* Abf = (unsigned short*)(ws);              // 33,554,432 B
  unsigned short* Tt  = (unsigned short*)(ws + 33554432);   // 16,777,216 B
  unsigned short* H1  = (unsigned short*)(ws + 50331648);   // 16,777,216 B
  float*          dinv = (float*)(ws + 67108864);           //    262,144 B
  unsigned short* W1p = (unsigned short*)(ws + 67371008);   //     32,768 B
  unsigned short* W2p = (unsigned short*)(ws + 67403776);   //     32,768 B

  k_packW<<<32, 64, 0, stream>>>(W1, W1p);
  k_packW<<<32, 64, 0, stream>>>(W2, W2p);
  k_deg_conv<<<2048, 256, 0, stream>>>(adj, Abf, dinv);
  k_feat<float><<<1024, 256, 0, stream>>>(x, W1p, dinv, Tt);
  k_agg<false><<<256, 512, 0, stream>>>(Abf, Tt, dinv, b1, H1, nullptr, nullptr, nullptr);
  k_feat<unsigned short><<<1024, 256, 0, stream>>>(H1, W2p, dinv, Tt);
  k_agg<true><<<256, 512, 0, stream>>>(Abf, Tt, dinv, b2, nullptr, Wr, br, out);
}

// Round 4
// 63.782 us; speedup vs baseline: 2.0326x; 1.6734x over previous
//
#include <hip/hip_runtime.h>
#include <cstddef>

// B=256 batches, N=256 nodes, F=128 features. One block per batch.

typedef __attribute__((ext_vector_type(8))) short short8;
typedef __attribute__((ext_vector_type(4))) float f32x4;

static __device__ __forceinline__ unsigned short f2bf(float f) {
  unsigned int u = __float_as_uint(f);
  u += 0x7FFFu + ((u >> 16) & 1u);   // round-nearest-even to bf16
  return (unsigned short)(u >> 16);
}

static __device__ __forceinline__ f32x4 mfma16(short8 a, short8 b, f32x4 c) {
  return __builtin_amdgcn_mfma_f32_16x16x32_bf16(a, b, c, 0, 0, 0);
}

static __device__ __forceinline__ short8 load_bfrag(const float* p) {
  float4 u = *reinterpret_cast<const float4*>(p);
  float4 v = *reinterpret_cast<const float4*>(p + 4);
  short8 f;
  f[0] = (short)f2bf(u.x); f[1] = (short)f2bf(u.y);
  f[2] = (short)f2bf(u.z); f[3] = (short)f2bf(u.w);
  f[4] = (short)f2bf(v.x); f[5] = (short)f2bf(v.y);
  f[6] = (short)f2bf(v.z); f[7] = (short)f2bf(v.w);
  return f;
}

// LDS byte addressing with XOR swizzle (T: [f][256] bf16, H: [n][128] bf16).
// Swizzle spreads stride-512B / stride-256B row reads across banks (2-way max).
static __device__ __forceinline__ int byteT(int f, int k) {
  return ((f << 9) + (k << 1)) ^ ((f & 7) << 4);
}
static __device__ __forceinline__ int byteH(int n, int k) {
  return ((n << 8) + (k << 1)) ^ ((n & 7) << 4);
}

// ---------------- pack W1 and W2 (128x128 f32) into MFMA A-fragment order ----
// frag elem j = W[ks*32+(l>>4)*8+j][r*16+(l&15)] at P[((ks*8+r)*64+l)*8+j].
__global__ __launch_bounds__(64) void k_packW2(
    const float* __restrict__ W1, const float* __restrict__ W2,
    unsigned short* __restrict__ P1, unsigned short* __restrict__ P2) {
  const float* W = (blockIdx.x < 32) ? W1 : W2;
  unsigned short* P = (blockIdx.x < 32) ? P1 : P2;
  const int bb = blockIdx.x & 31;
  const int ks = bb >> 3;
  const int r = bb & 7;
  const int l = threadIdx.x;
  const int col = r * 16 + (l & 15);
  const int k0 = ks * 32 + ((l >> 4) << 3);
  short8 frag;
  #pragma unroll
  for (int j = 0; j < 8; ++j)
    frag[j] = (short)f2bf(W[(size_t)(k0 + j) * 128 + col]);
  *reinterpret_cast<short8*>(P + ((size_t)((ks * 8 + r) * 64 + l)) * 8) = frag;
}

// ---------------- fully fused GCN: deg + 2 layers + pool + readout ----------
__global__ __launch_bounds__(512) void k_fused(
    const float* __restrict__ adj, const float* __restrict__ x,
    const unsigned short* __restrict__ W1p, const unsigned short* __restrict__ W2p,
    const float* __restrict__ b1, const float* __restrict__ b2,
    const float* __restrict__ Wr, const float* __restrict__ br,
    unsigned short* __restrict__ Abf, float* __restrict__ out) {
  __shared__ __align__(16) char bufA[65536];   // T1 then T2: [f][256] bf16 swz
  __shared__ __align__(16) char bufB[65536];   // P0 colsum red / H1 / pool bufs
  __shared__ float dinv_s[256];

  const int b = blockIdx.x;
  const int tid = threadIdx.x;
  const int w = tid >> 6;          // wave 0..7
  const int l = tid & 63;
  const int l15 = l & 15;
  const int khalf = (l >> 4) << 3;
  const int qbase = (l >> 4) << 2;

  // ---- P0: colsum degree (adj symmetric => colsum==rowsum), diag:=1,
  //          bf16 convert -> Abf (global ws, L2/L3-hot for P2/P4) ----
  {
    const int cq = tid & 63;       // column quad
    const int rg = tid >> 6;       // row group (== wave)
    const int c0 = cq << 2;
    const float* adjb = adj + ((size_t)b << 16);
    unsigned short* Ab = Abf + ((size_t)b << 16);
    float sx = 0.f, sy = 0.f, sz = 0.f, sw = 0.f;
    #pragma unroll 4
    for (int i = 0; i < 32; ++i) {
      const int r = (rg << 5) + i;
      float4 v = *reinterpret_cast<const float4*>(adjb + r * 256 + c0);
      v.x = (r == c0 + 0) ? 1.0f : v.x;
      v.y = (r == c0 + 1) ? 1.0f : v.y;
      v.z = (r == c0 + 2) ? 1.0f : v.z;
      v.w = (r == c0 + 3) ? 1.0f : v.w;
      sx += v.x; sy += v.y; sz += v.z; sw += v.w;
      ushort4 o;
      o.x = f2bf(v.x); o.y = f2bf(v.y); o.z = f2bf(v.z); o.w = f2bf(v.w);
      *reinterpret_cast<ushort4*>(Ab + r * 256 + c0) = o;
    }
    float* red = reinterpret_cast<float*>(bufB);   // [8][256]
    float4 st; st.x = sx; st.y = sy; st.z = sz; st.w = sw;
    *reinterpret_cast<float4*>(red + (rg << 8) + c0) = st;
  }
  __syncthreads();
  if (tid < 256) {
    const float* red = reinterpret_cast<const float*>(bufB);
    float s = 0.f;
    #pragma unroll
    for (int g = 0; g < 8; ++g) s += red[(g << 8) + tid];
    dinv_s[tid] = rsqrtf(fmaxf(s, 1.0f));
  }
  __syncthreads();

  // ---- P1: T1[f][m] = dinv[m] * (x@W1)[m][f] -> bufA (swizzled) ----
  {
    const short8* Wf = reinterpret_cast<const short8*>(W1p);
    for (int p = 0; p < 2; ++p) {
      const int m = (p << 7) + (w << 4) + l15;
      const float* xr = x + ((((size_t)b << 8) + m) << 7);
      f32x4 acc[8];
      #pragma unroll
      for (int r = 0; r < 8; ++r) acc[r] = (f32x4)(0.0f);
      #pragma unroll
      for (int ks = 0; ks < 4; ++ks) {
        short8 bf = load_bfrag(xr + (ks << 5) + khalf);
        #pragma unroll
        for (int r = 0; r < 8; ++r)
          acc[r] = mfma16(Wf[((ks << 3) + r) * 64 + l], bf, acc[r]);
      }
      const float sc = dinv_s[m];
      #pragma unroll
      for (int r = 0; r < 8; ++r) {
        #pragma unroll
        for (int q = 0; q < 4; ++q) {
          const int f = (r << 4) + qbase + q;
          *reinterpret_cast<unsigned short*>(bufA + byteT(f, m)) =
              f2bf(acc[r][q] * sc);
        }
      }
    }
  }
  __syncthreads();

  // ---- P2: H1[n][f] = dinv[n]*(A'@T1)[n][f] + b1 -> bufB (swizzled) ----
  {
    const unsigned short* Ab = Abf + ((size_t)b << 16);
    const int n0w = w << 5;
    float bs[8];
    #pragma unroll
    for (int c = 0; c < 8; ++c) bs[c] = b1[(c << 4) + l15];
    f32x4 acc[2][8];
    #pragma unroll
    for (int rt = 0; rt < 2; ++rt)
      #pragma unroll
      for (int c = 0; c < 8; ++c) acc[rt][c] = (f32x4)(0.0f);
    #pragma unroll
    for (int ks = 0; ks < 8; ++ks) {
      const int k0 = (ks << 5) + khalf;
      short8 a0 = *reinterpret_cast<const short8*>(Ab + (size_t)(n0w + l15) * 256 + k0);
      short8 a1 = *reinterpret_cast<const short8*>(Ab + (size_t)(n0w + 16 + l15) * 256 + k0);
      #pragma unroll
      for (int c = 0; c < 8; ++c) {
        short8 bf = *reinterpret_cast<const short8*>(bufA + byteT((c << 4) + l15, k0));
        acc[0][c] = mfma16(a0, bf, acc[0][c]);
        acc[1][c] = mfma16(a1, bf, acc[1][c]);
      }
    }
    #pragma unroll
    for (int rt = 0; rt < 2; ++rt) {
      #pragma unroll
      for (int q = 0; q < 4; ++q) {
        const int n = n0w + (rt << 4) + qbase + q;
        const float dv = dinv_s[n];
        #pragma unroll
        for (int c = 0; c < 8; ++c) {
          const int f = (c << 4) + l15;
          *reinterpret_cast<unsigned short*>(bufB + byteH(n, f)) =
              f2bf(acc[rt][c][q] * dv + bs[c]);
        }
      }
    }
  }
  __syncthreads();

  // ---- P3: T2[f][m] = dinv[m] * (H1@W2)[m][f] -> bufA (swizzled) ----
  {
    const short8* Wf = reinterpret_cast<const short8*>(W2p);
    for (int p = 0; p < 2; ++p) {
      const int m = (p << 7) + (w << 4) + l15;
      f32x4 acc[8];
      #pragma unroll
      for (int r = 0; r < 8; ++r) acc[r] = (f32x4)(0.0f);
      #pragma unroll
      for (int ks = 0; ks < 4; ++ks) {
        const int kk = (ks << 5) + khalf;
        short8 bf = *reinterpret_cast<const short8*>(bufB + byteH(m, kk));
        #pragma unroll
        for (int r = 0; r < 8; ++r)
          acc[r] = mfma16(Wf[((ks << 3) + r) * 64 + l], bf, acc[r]);
      }
      const float sc = dinv_s[m];
      #pragma unroll
      for (int r = 0; r < 8; ++r) {
        #pragma unroll
        for (int q = 0; q < 4; ++q) {
          const int f = (r << 4) + qbase + q;
          *reinterpret_cast<unsigned short*>(bufA + byteT(f, m)) =
              f2bf(acc[r][q] * sc);
        }
      }
    }
  }
  __syncthreads();

  // ---- P4: H2 = dinv*(A'@T2)+b2 (regs only) + mean/max pool + readout ----
  {
    const unsigned short* Ab = Abf + ((size_t)b << 16);
    const int n0w = w << 5;
    float bs[8];
    #pragma unroll
    for (int c = 0; c < 8; ++c) bs[c] = b2[(c << 4) + l15];
    f32x4 acc[2][8];
    #pragma unroll
    for (int rt = 0; rt < 2; ++rt)
      #pragma unroll
      for (int c = 0; c < 8; ++c) acc[rt][c] = (f32x4)(0.0f);
    #pragma unroll
    for (int ks = 0; ks < 8; ++ks) {
      const int k0 = (ks << 5) + khalf;
      short8 a0 = *reinterpret_cast<const short8*>(Ab + (size_t)(n0w + l15) * 256 + k0);
      short8 a1 = *reinterpret_cast<const short8*>(Ab + (size_t)(n0w + 16 + l15) * 256 + k0);
      #pragma unroll
      for (int c = 0; c < 8; ++c) {
        short8 bf = *reinterpret_cast<const short8*>(bufA + byteT((c << 4) + l15, k0));
        acc[0][c] = mfma16(a0, bf, acc[0][c]);
        acc[1][c] = mfma16(a1, bf, acc[1][c]);
      }
    }
    float psum[8], pmax[8];
    #pragma unroll
    for (int c = 0; c < 8; ++c) { psum[c] = 0.0f; pmax[c] = -1e30f; }
    #pragma unroll
    for (int rt = 0; rt < 2; ++rt) {
      #pragma unroll
      for (int q = 0; q < 4; ++q) {
        const int n = n0w + (rt << 4) + qbase + q;
        const float dv = dinv_s[n];
        #pragma unroll
        for (int c = 0; c < 8; ++c) {
          const float v = acc[rt][c][q] * dv + bs[c];
          psum[c] += v;
          pmax[c] = fmaxf(pmax[c], v);
        }
      }
    }
    // reduce across the 4 lane-groups sharing the same f (=c*16+l15)
    #pragma unroll
    for (int c = 0; c < 8; ++c) {
      psum[c] += __shfl_xor(psum[c], 16);
      pmax[c] = fmaxf(pmax[c], __shfl_xor(pmax[c], 16));
      psum[c] += __shfl_xor(psum[c], 32);
      pmax[c] = fmaxf(pmax[c], __shfl_xor(pmax[c], 32));
    }
    float* lds_sum = reinterpret_cast<float*>(bufB);      // [8][128]
    float* lds_max = lds_sum + 1024;                      // [8][128]
    float* pooled = lds_max + 1024;                       // [256]
    if (l < 16) {
      #pragma unroll
      for (int c = 0; c < 8; ++c) {
        lds_sum[(w << 7) + (c << 4) + l] = psum[c];
        lds_max[(w << 7) + (c << 4) + l] = pmax[c];
      }
    }
    __syncthreads();
    if (tid < 128) {
      float s = 0.0f, m = -1e30f;
      #pragma unroll
      for (int ww = 0; ww < 8; ++ww) {
        s += lds_sum[(ww << 7) + tid];
        m = fmaxf(m, lds_max[(ww << 7) + tid]);
      }
      pooled[tid] = s * (1.0f / 256.0f);
      pooled[128 + tid] = m;
    }
    __syncthreads();
    if (tid < 128) {
      float o0 = 0.f, o1 = 0.f, o2 = 0.f, o3 = 0.f;
      for (int i = 0; i < 256; i += 4) {
        o0 = fmaf(pooled[i + 0], Wr[(i + 0) * 128 + tid], o0);
        o1 = fmaf(pooled[i + 1], Wr[(i + 1) * 128 + tid], o1);
        o2 = fmaf(pooled[i + 2], Wr[(i + 2) * 128 + tid], o2);
        o3 = fmaf(pooled[i + 3], Wr[(i + 3) * 128 + tid], o3);
      }
      out[(b << 7) + tid] = ((o0 + o1) + (o2 + o3)) + br[tid];
    }
  }
}

extern "C" void kernel_launch(void* const* d_in, const int* in_sizes, int n_in,
                              void* d_out, int out_size, void* d_ws, size_t ws_size,
                              hipStream_t stream) {
  const float* x   = (const float*)d_in[0];
  const float* adj = (const float*)d_in[1];
  const float* W1  = (const float*)d_in[2];
  const float* b1  = (const float*)d_in[3];
  const float* W2  = (const float*)d_in[4];
  const float* b2  = (const float*)d_in[5];
  const float* Wr  = (const float*)d_in[6];
  const float* br  = (const float*)d_in[7];
  float* out = (float*)d_out;

  char* ws = (char*)d_ws;
  unsigned short* Abf = (unsigned short*)(ws);              // 33,554,432 B
  unsigned short* W1p = (unsigned short*)(ws + 33554432);   //     32,768 B
  unsigned short* W2p = (unsigned short*)(ws + 33587200);   //     32,768 B

  k_packW2<<<64, 64, 0, stream>>>(W1, W2, W1p, W2p);
  k_fused<<<256, 512, 0, stream>>>(adj, x, W1p, W2p, b1, b2, Wr, br, Abf, out);
}